// Round 4
// baseline (489.606 us; speedup 1.0000x reference)
//
#include <hip/hip_runtime.h>

#define N_NODES 100000
#define N_PAD   100032
#define N_EDGES 1600000
#define HID 128
#define N_PRED 8

#define BSHIFT 7                       // 128 nodes per bucket
#define NBUCK  782                     // ceil(100000/128)
#define CHUNK  8192                    // edges per sort block
#define NCHUNK 196                     // ceil(1600000/8192)
#define MAXB   3072                    // LDS capacity per bucket (avg 2047)

#define LROW 136                       // LDS row stride in shorts (128 + 8 pad)

typedef __attribute__((ext_vector_type(8))) short short8;
typedef __attribute__((ext_vector_type(4))) float f32x4;

__device__ __forceinline__ unsigned short f2bf(float f) {
    union { float f; unsigned u; } c; c.f = f;
    unsigned u = c.u;
    u += 0x7fffu + ((u >> 16) & 1u);   // RNE
    return (unsigned short)(u >> 16);
}
__device__ __forceinline__ float bflo(unsigned u) {
    union { unsigned u; float f; } c; c.u = u << 16; return c.f;
}
__device__ __forceinline__ float bfhi(unsigned u) {
    union { unsigned u; float f; } c; c.u = u & 0xffff0000u; return c.f;
}

// ============ degree-out histogram (dedicated, full occupancy) ============
__global__ void deg_kernel(const int* __restrict__ src, unsigned* __restrict__ degOut) {
    int e = blockIdx.x * 256 + threadIdx.x;
    if (e < N_EDGES) atomicAdd(&degOut[src[e]], 1u);
}

__global__ void normout_kernel(const unsigned* __restrict__ degOut, float* __restrict__ normOut) {
    int i = blockIdx.x * 256 + threadIdx.x;
    if (i < N_NODES) {
        unsigned d = degOut[i];
        normOut[i] = d ? rsqrtf((float)d) : 0.0f;
    }
}

// ============ CSR build: bucket sort by dst ============

// B1: per-block bucket histogram (LDS only)
__global__ void bucket_hist(const int* __restrict__ dst, unsigned* __restrict__ blockHist) {
    __shared__ unsigned hist[NBUCK];
    for (int i = threadIdx.x; i < NBUCK; i += 256) hist[i] = 0u;
    __syncthreads();
    int base = blockIdx.x * CHUNK;
    int lim = min(base + CHUNK, N_EDGES);
    for (int e = base + threadIdx.x; e < lim; e += 256)
        atomicAdd(&hist[((unsigned)dst[e]) >> BSHIFT], 1u);
    __syncthreads();
    for (int i = threadIdx.x; i < NBUCK; i += 256)
        blockHist[(size_t)i * NCHUNK + blockIdx.x] = hist[i];   // bucket-major
}

// B2a: bucket totals
__global__ void bucket_total(const unsigned* __restrict__ blockHist, unsigned* __restrict__ bucketTotal) {
    __shared__ unsigned red[256];
    int t = threadIdx.x;
    red[t] = (t < NCHUNK) ? blockHist[(size_t)blockIdx.x * NCHUNK + t] : 0u;
    __syncthreads();
    for (int s = 128; s > 0; s >>= 1) {
        if (t < s) red[t] += red[t + s];
        __syncthreads();
    }
    if (t == 0) bucketTotal[blockIdx.x] = red[0];
}

// B2b: exclusive scan of bucket totals -> bucketBase (single block)
__global__ void bucket_scan(const unsigned* __restrict__ bucketTotal, unsigned* __restrict__ bucketBase) {
    __shared__ unsigned tmp[1024];
    int t = threadIdx.x;
    unsigned v = (t < NBUCK) ? bucketTotal[t] : 0u;
    tmp[t] = v;
    __syncthreads();
    for (int off = 1; off < 1024; off <<= 1) {
        unsigned a = (t >= off) ? tmp[t - off] : 0u;
        __syncthreads();
        tmp[t] += a;
        __syncthreads();
    }
    if (t < NBUCK) bucketBase[t] = tmp[t] - v;   // exclusive
}

// B2c: per-bucket exclusive scan of per-block counts + bucketBase -> absolute cursors
__global__ void bucket_cursor(unsigned* __restrict__ blockHist, const unsigned* __restrict__ bucketBase) {
    __shared__ unsigned tmp[256];
    int t = threadIdx.x;
    unsigned v = (t < NCHUNK) ? blockHist[(size_t)blockIdx.x * NCHUNK + t] : 0u;
    tmp[t] = v;
    __syncthreads();
    for (int off = 1; off < 256; off <<= 1) {
        unsigned a = (t >= off) ? tmp[t - off] : 0u;
        __syncthreads();
        tmp[t] += a;
        __syncthreads();
    }
    if (t < NCHUNK)
        blockHist[(size_t)blockIdx.x * NCHUNK + t] = tmp[t] - v + bucketBase[blockIdx.x];
}

// B3: scatter packed edges into bucket order (block-owned runs -> L2 line merging)
__global__ void bucket_scatter(const int* __restrict__ src, const int* __restrict__ dst,
                               const unsigned* __restrict__ blockHist, unsigned* __restrict__ bucketed) {
    __shared__ unsigned cursor[NBUCK];
    for (int i = threadIdx.x; i < NBUCK; i += 256)
        cursor[i] = blockHist[(size_t)i * NCHUNK + blockIdx.x];
    __syncthreads();
    int base = blockIdx.x * CHUNK;
    int lim = min(base + CHUNK, N_EDGES);
    for (int e = base + threadIdx.x; e < lim; e += 256) {
        unsigned d = (unsigned)dst[e];
        unsigned p = atomicAdd(&cursor[d >> BSHIFT], 1u);
        bucketed[p] = ((d & 127u) << 17) | (unsigned)src[e];   // src < 2^17
    }
}

// C: per-bucket placement in LDS; emits csrSrc (coalesced), rowEnd, normIn
__global__ void bucket_place(const unsigned* __restrict__ bucketed,
                             const unsigned* __restrict__ bucketBase,
                             int* __restrict__ csrSrc, unsigned* __restrict__ rowEnd,
                             float* __restrict__ normIn) {
    __shared__ unsigned cnt128[128], cur[128];
    __shared__ unsigned eb[MAXB], ob[MAXB];
    int b = blockIdx.x;
    unsigned s0 = bucketBase[b];
    unsigned s1 = (b + 1 < NBUCK) ? bucketBase[b + 1] : (unsigned)N_EDGES;
    int cnt = (int)(s1 - s0);
    bool fits = cnt <= MAXB;
    int t = threadIdx.x;
    if (t < 128) cnt128[t] = 0u;
    __syncthreads();
    for (int i = t; i < cnt; i += 256) {
        unsigned v = bucketed[s0 + i];
        if (fits) eb[i] = v;
        atomicAdd(&cnt128[v >> 17], 1u);
    }
    __syncthreads();
    unsigned deg = (t < 128) ? cnt128[t] : 0u;
    __syncthreads();
    for (int off = 1; off < 128; off <<= 1) {
        unsigned a = (t < 128 && t >= off) ? cnt128[t - off] : 0u;
        __syncthreads();
        if (t < 128) cnt128[t] += a;
        __syncthreads();
    }
    if (t < 128) {
        unsigned incl = cnt128[t];
        cur[t] = incl - deg;               // local exclusive
        int node = b * 128 + t;
        if (node < N_NODES) {
            rowEnd[node] = s0 + incl;      // global inclusive prefix
            normIn[node] = deg ? rsqrtf((float)deg) : 0.0f;
        }
    }
    __syncthreads();
    if (fits) {
        for (int i = t; i < cnt; i += 256) {
            unsigned v = eb[i];
            unsigned p = atomicAdd(&cur[v >> 17], 1u);
            ob[p] = v & 0x1FFFFu;
        }
        __syncthreads();
        for (int i = t; i < cnt; i += 256)
            csrSrc[s0 + i] = (int)ob[i];
    } else {
        for (int i = t; i < cnt; i += 256) {
            unsigned v = bucketed[s0 + i];
            unsigned p = atomicAdd(&cur[v >> 17], 1u);
            csrSrc[s0 + p] = (int)(v & 0x1FFFFu);
        }
    }
}

// ============ datapath ============

__global__ void convert_kernel(const float* __restrict__ feat, const float* __restrict__ normOut,
                               unsigned short* __restrict__ out) {
    int gid = blockIdx.x * 256 + threadIdx.x;
    if (gid >= N_NODES * 32) return;
    int row = gid >> 5, j = gid & 31;
    float no = normOut[row];
    float4 v = ((const float4*)feat)[(size_t)row * 32 + j];
    ushort4 o;
    o.x = f2bf(v.x * no); o.y = f2bf(v.y * no);
    o.z = f2bf(v.z * no); o.w = f2bf(v.w * no);
    ((ushort4*)out)[(size_t)row * 32 + j] = o;
}

__device__ __forceinline__ void acc8(float* a, uint4 v) {
    a[0] += bflo(v.x); a[1] += bfhi(v.x);
    a[2] += bflo(v.y); a[3] += bfhi(v.y);
    a[4] += bflo(v.z); a[5] += bfhi(v.z);
    a[6] += bflo(v.w); a[7] += bfhi(v.w);
}

// repack 3 weights (fp32 KxN) into bf16 B-fragment order; blockIdx>>3 selects the matrix
__global__ void repack_kernel(const float* __restrict__ W0, const float* __restrict__ W1,
                              const float* __restrict__ W2,
                              unsigned short* __restrict__ Wp0, unsigned short* __restrict__ Wp1,
                              unsigned short* __restrict__ Wp2) {
    int which = blockIdx.x >> 3;
    const float* W = which == 0 ? W0 : which == 1 ? W1 : W2;
    unsigned short* Wp = which == 0 ? Wp0 : which == 1 ? Wp1 : Wp2;
    int tid = (blockIdx.x & 7) * 256 + threadIdx.x;
    int tile = tid >> 6, lane = tid & 63;
    int n_tile = tile >> 2, k_tile = tile & 3;
    int n = n_tile * 16 + (lane & 15);
    int k0 = k_tile * 32 + (lane >> 4) * 8;
    unsigned short v[8];
#pragma unroll
    for (int j = 0; j < 8; ++j)
        v[j] = f2bf(W[(size_t)(k0 + j) * 128 + n]);
    uint4 o;
    o.x = (unsigned)v[0] | ((unsigned)v[1] << 16);
    o.y = (unsigned)v[2] | ((unsigned)v[3] << 16);
    o.z = (unsigned)v[4] | ((unsigned)v[5] << 16);
    o.w = (unsigned)v[6] | ((unsigned)v[7] << 16);
    *(uint4*)&Wp[(size_t)(tile * 64 + lane) * 8] = o;
}

// ============ fused gather + MFMA GEMM + epilogue ============
// Per block: 64 dst rows. Phase 1: gather neighbor sums into LDS (bf16).
// Phase 2: A-frags from LDS, B-frags from Wp, 16x16x32 MFMA.
// Epilogue: relu(normIn*acc + b) [* postScale], store bf16.
__launch_bounds__(256)
__global__ void fused_layer(const unsigned short* __restrict__ h,
                            const int* __restrict__ csrSrc,
                            const unsigned* __restrict__ rowEnd,
                            const unsigned short* __restrict__ Wp,
                            const float* __restrict__ bias,
                            const float* __restrict__ normIn,
                            const float* __restrict__ postScale,
                            unsigned short* __restrict__ Out) {
    __shared__ unsigned short Ml[64 * LROW];   // 17408 B
    int tid = threadIdx.x;
    int slot = tid >> 4, lane16 = tid & 15;    // 16 slots x 16 lanes
    int rowBase = blockIdx.x * 64;
    const uint4* h4 = (const uint4*)h;

#pragma unroll
    for (int j = 0; j < 4; ++j) {
        int rloc = slot + 16 * j;
        int row = rowBase + rloc;
        float a[8] = {0.f, 0.f, 0.f, 0.f, 0.f, 0.f, 0.f, 0.f};
        if (row < N_NODES) {
            unsigned start = row ? rowEnd[row - 1] : 0u;
            unsigned end = rowEnd[row];
            unsigned k = start;
            for (; k + 8 <= end; k += 8) {
                int s[8];
#pragma unroll
                for (int u = 0; u < 8; ++u) s[u] = csrSrc[k + u];
                uint4 v[8];
#pragma unroll
                for (int u = 0; u < 8; ++u) v[u] = h4[(size_t)s[u] * 16 + lane16];
#pragma unroll
                for (int u = 0; u < 8; ++u) acc8(a, v[u]);
            }
            if (k + 4 <= end) {
                int s[4];
#pragma unroll
                for (int u = 0; u < 4; ++u) s[u] = csrSrc[k + u];
                uint4 v[4];
#pragma unroll
                for (int u = 0; u < 4; ++u) v[u] = h4[(size_t)s[u] * 16 + lane16];
#pragma unroll
                for (int u = 0; u < 4; ++u) acc8(a, v[u]);
                k += 4;
            }
            for (; k < end; ++k) {
                uint4 v = h4[(size_t)csrSrc[k] * 16 + lane16];
                acc8(a, v);
            }
        }
        uint4 o;
        o.x = (unsigned)f2bf(a[0]) | ((unsigned)f2bf(a[1]) << 16);
        o.y = (unsigned)f2bf(a[2]) | ((unsigned)f2bf(a[3]) << 16);
        o.z = (unsigned)f2bf(a[4]) | ((unsigned)f2bf(a[5]) << 16);
        o.w = (unsigned)f2bf(a[6]) | ((unsigned)f2bf(a[7]) << 16);
        *(uint4*)&Ml[rloc * LROW + lane16 * 8] = o;
    }
    __syncthreads();

    int wave = tid >> 6, lane = tid & 63;
    int mrow = lane & 15, quad = lane >> 4;
    int rloc = wave * 16 + mrow;
    short8 afr[4];
#pragma unroll
    for (int kt = 0; kt < 4; ++kt)
        afr[kt] = *(const short8*)&Ml[rloc * LROW + kt * 32 + quad * 8];

    f32x4 acc[8];
#pragma unroll
    for (int nt = 0; nt < 8; ++nt) {
        f32x4 c = {0.f, 0.f, 0.f, 0.f};
#pragma unroll
        for (int kt = 0; kt < 4; ++kt) {
            short8 b = *(const short8*)&Wp[(size_t)((nt * 4 + kt) * 64 + lane) * 8];
            c = __builtin_amdgcn_mfma_f32_16x16x32_bf16(afr[kt], b, c, 0, 0, 0);
        }
        acc[nt] = c;
    }

    int col0 = lane & 15;
#pragma unroll
    for (int r = 0; r < 4; ++r) {
        int row = rowBase + wave * 16 + quad * 4 + r;
        if (row >= N_NODES) continue;
        float ni = normIn[row];
        float po = postScale ? postScale[row] : 1.0f;
#pragma unroll
        for (int nt = 0; nt < 8; ++nt) {
            float v = fmaxf(fmaf(acc[nt][r], ni, bias[nt * 16 + col0]), 0.f) * po;
            Out[(size_t)row * 128 + nt * 16 + col0] = f2bf(v);
        }
    }
}

__global__ void mean_kernel(const unsigned short* __restrict__ h, float* __restrict__ hg) {
    __shared__ float red[4][128];
    int c2 = threadIdx.x & 63;
    int rq = threadIdx.x >> 6;
    float a0 = 0.f, a1 = 0.f;
    for (int i = blockIdx.x * 4 + rq; i < N_NODES; i += gridDim.x * 4) {
        unsigned u = *(const unsigned*)&h[(size_t)i * 128 + c2 * 2];
        a0 += bflo(u); a1 += bfhi(u);
    }
    red[rq][c2 * 2] = a0; red[rq][c2 * 2 + 1] = a1;
    __syncthreads();
    if (threadIdx.x < 128) {
        float s = red[0][threadIdx.x] + red[1][threadIdx.x] +
                  red[2][threadIdx.x] + red[3][threadIdx.x];
        atomicAdd(&hg[threadIdx.x], s);
    }
}

__global__ void final_kernel(const float* __restrict__ hg, const float* __restrict__ Wr,
                             const float* __restrict__ br, float* __restrict__ out) {
    int j = threadIdx.x;
    if (j < N_PRED) {
        float acc = br[j];
        const float inv = 1.0f / (float)N_NODES;
        for (int k = 0; k < HID; ++k)
            acc = fmaf(hg[k] * inv, Wr[k * N_PRED + j], acc);
        out[j] = acc;
    }
}

extern "C" void kernel_launch(void* const* d_in, const int* in_sizes, int n_in,
                              void* d_out, int out_size, void* d_ws, size_t ws_size,
                              hipStream_t stream) {
    const float* features = (const float*)d_in[0];
    const float* W0 = (const float*)d_in[1];
    const float* b0 = (const float*)d_in[2];
    const float* W1 = (const float*)d_in[3];
    const float* b1 = (const float*)d_in[4];
    const float* W2 = (const float*)d_in[5];
    const float* b2 = (const float*)d_in[6];
    const float* Wr = (const float*)d_in[7];
    const float* br = (const float*)d_in[8];
    const int* src = (const int*)d_in[9];
    const int* dst = (const int*)d_in[10];
    float* out = (float*)d_out;

    char* ws = (char*)d_ws;
    size_t off = 0;
    auto alloc = [&](size_t bytes) -> void* {
        void* p = ws + off;
        off = (off + bytes + 255) & ~(size_t)255;
        return p;
    };
    unsigned short* buf0 = (unsigned short*)alloc((size_t)N_PAD * HID * 2);
    unsigned short* buf1 = (unsigned short*)alloc((size_t)N_PAD * HID * 2);
    unsigned short* Wp0 = (unsigned short*)alloc(128 * 128 * 2);
    unsigned short* Wp1 = (unsigned short*)alloc(128 * 128 * 2);
    unsigned short* Wp2 = (unsigned short*)alloc(128 * 128 * 2);
    unsigned* degOut = (unsigned*)alloc(N_NODES * 4);
    float* normOut = (float*)alloc(N_NODES * 4);
    float* normIn = (float*)alloc(N_NODES * 4);
    unsigned* rowEnd = (unsigned*)alloc(N_NODES * 4);
    unsigned* blockHist = (unsigned*)alloc((size_t)NBUCK * NCHUNK * 4);
    unsigned* bucketTotal = (unsigned*)alloc(NBUCK * 4);
    unsigned* bucketBase = (unsigned*)alloc((NBUCK + 1) * 4);
    unsigned* bucketed = (unsigned*)alloc((size_t)N_EDGES * 4);
    int* csrSrc = (int*)alloc((size_t)N_EDGES * 4);
    float* hg = (float*)alloc(HID * 4);

    hipMemsetAsync(degOut, 0, N_NODES * 4, stream);
    hipMemsetAsync(hg, 0, HID * 4, stream);

    deg_kernel<<<(N_EDGES + 255) / 256, 256, 0, stream>>>(src, degOut);
    bucket_hist<<<NCHUNK, 256, 0, stream>>>(dst, blockHist);
    bucket_total<<<NBUCK, 256, 0, stream>>>(blockHist, bucketTotal);
    bucket_scan<<<1, 1024, 0, stream>>>(bucketTotal, bucketBase);
    bucket_cursor<<<NBUCK, 256, 0, stream>>>(blockHist, bucketBase);
    bucket_scatter<<<NCHUNK, 256, 0, stream>>>(src, dst, blockHist, bucketed);
    bucket_place<<<NBUCK, 256, 0, stream>>>(bucketed, bucketBase, csrSrc, rowEnd, normIn);
    normout_kernel<<<(N_NODES + 255) / 256, 256, 0, stream>>>(degOut, normOut);

    convert_kernel<<<(N_NODES * 32 + 255) / 256, 256, 0, stream>>>(features, normOut, buf0);
    repack_kernel<<<24, 256, 0, stream>>>(W0, W1, W2, Wp0, Wp1, Wp2);

    int fusedGrid = (N_NODES + 63) / 64;   // 1563

    fused_layer<<<fusedGrid, 256, 0, stream>>>(buf0, csrSrc, rowEnd, Wp0, b0, normIn, normOut, buf1);
    fused_layer<<<fusedGrid, 256, 0, stream>>>(buf1, csrSrc, rowEnd, Wp1, b1, normIn, normOut, buf0);
    fused_layer<<<fusedGrid, 256, 0, stream>>>(buf0, csrSrc, rowEnd, Wp2, b2, normIn,
                                               (const float*)nullptr, buf1);

    mean_kernel<<<240, 256, 0, stream>>>(buf1, hg);
    final_kernel<<<1, 64, 0, stream>>>(hg, Wr, br, out);
}

// Round 5
// 413.842 us; speedup vs baseline: 1.1831x; 1.1831x over previous
//
#include <hip/hip_runtime.h>

#define N_NODES 100000
#define N_PAD   100032
#define N_EDGES 1600000
#define HID 128
#define N_PRED 8

#define BSHIFT 7                       // 128 nodes per bucket
#define NBUCK  782                     // ceil(100000/128)
#define CHUNK  8192                    // edges per sort block
#define NCHUNK 196                     // ceil(1600000/8192)
#define MAXB   3072                    // LDS capacity per bucket (avg 2047)

#define LROW 136                       // LDS row stride in shorts (128 + 8 pad)

typedef __attribute__((ext_vector_type(8))) short short8;
typedef __attribute__((ext_vector_type(4))) float f32x4;
typedef __attribute__((ext_vector_type(2))) float f32x2;

__device__ __forceinline__ unsigned short f2bf(float f) {
    union { float f; unsigned u; } c; c.f = f;
    unsigned u = c.u;
    u += 0x7fffu + ((u >> 16) & 1u);   // RNE
    return (unsigned short)(u >> 16);
}

// fp8 e4m3 (OCP) helpers
__device__ __forceinline__ unsigned char f2fp8(float v) {
    unsigned w = __builtin_amdgcn_cvt_pk_fp8_f32(v, v, 0, false);
    return (unsigned char)(w & 0xff);
}

// ============ degree-out histogram ============
__global__ void deg_kernel(const int4* __restrict__ src4, unsigned* __restrict__ degOut) {
    int i = blockIdx.x * 256 + threadIdx.x;
    if (i < N_EDGES / 4) {
        int4 s = src4[i];
        atomicAdd(&degOut[s.x], 1u);
        atomicAdd(&degOut[s.y], 1u);
        atomicAdd(&degOut[s.z], 1u);
        atomicAdd(&degOut[s.w], 1u);
    }
}

__global__ void normout_kernel(const unsigned* __restrict__ degOut, float* __restrict__ normOut) {
    int i = blockIdx.x * 256 + threadIdx.x;
    if (i < N_NODES) {
        unsigned d = degOut[i];
        normOut[i] = d ? rsqrtf((float)d) : 0.0f;
    }
}

// ============ CSR build: bucket sort by dst ============

__global__ void bucket_hist(const int* __restrict__ dst, unsigned* __restrict__ blockHist) {
    __shared__ unsigned hist[NBUCK];
    for (int i = threadIdx.x; i < NBUCK; i += 512) hist[i] = 0u;
    __syncthreads();
    int base = blockIdx.x * CHUNK;
    int lim = min(base + CHUNK, N_EDGES);
    for (int e = base + threadIdx.x; e < lim; e += 512)
        atomicAdd(&hist[((unsigned)dst[e]) >> BSHIFT], 1u);
    __syncthreads();
    for (int i = threadIdx.x; i < NBUCK; i += 512)
        blockHist[(size_t)i * NCHUNK + blockIdx.x] = hist[i];   // bucket-major
}

__global__ void bucket_total(const unsigned* __restrict__ blockHist, unsigned* __restrict__ bucketTotal) {
    __shared__ unsigned red[256];
    int t = threadIdx.x;
    red[t] = (t < NCHUNK) ? blockHist[(size_t)blockIdx.x * NCHUNK + t] : 0u;
    __syncthreads();
    for (int s = 128; s > 0; s >>= 1) {
        if (t < s) red[t] += red[t + s];
        __syncthreads();
    }
    if (t == 0) bucketTotal[blockIdx.x] = red[0];
}

__global__ void bucket_scan(const unsigned* __restrict__ bucketTotal, unsigned* __restrict__ bucketBase) {
    __shared__ unsigned tmp[1024];
    int t = threadIdx.x;
    unsigned v = (t < NBUCK) ? bucketTotal[t] : 0u;
    tmp[t] = v;
    __syncthreads();
    for (int off = 1; off < 1024; off <<= 1) {
        unsigned a = (t >= off) ? tmp[t - off] : 0u;
        __syncthreads();
        tmp[t] += a;
        __syncthreads();
    }
    if (t < NBUCK) bucketBase[t] = tmp[t] - v;   // exclusive
}

__global__ void bucket_cursor(unsigned* __restrict__ blockHist, const unsigned* __restrict__ bucketBase) {
    __shared__ unsigned tmp[256];
    int t = threadIdx.x;
    unsigned v = (t < NCHUNK) ? blockHist[(size_t)blockIdx.x * NCHUNK + t] : 0u;
    tmp[t] = v;
    __syncthreads();
    for (int off = 1; off < 256; off <<= 1) {
        unsigned a = (t >= off) ? tmp[t - off] : 0u;
        __syncthreads();
        tmp[t] += a;
        __syncthreads();
    }
    if (t < NCHUNK)
        blockHist[(size_t)blockIdx.x * NCHUNK + t] = tmp[t] - v + bucketBase[blockIdx.x];
}

__global__ void bucket_scatter(const int* __restrict__ src, const int* __restrict__ dst,
                               const unsigned* __restrict__ blockHist, unsigned* __restrict__ bucketed) {
    __shared__ unsigned cursor[NBUCK];
    for (int i = threadIdx.x; i < NBUCK; i += 512)
        cursor[i] = blockHist[(size_t)i * NCHUNK + blockIdx.x];
    __syncthreads();
    int base = blockIdx.x * CHUNK;
    int lim = min(base + CHUNK, N_EDGES);
    for (int e = base + threadIdx.x; e < lim; e += 512) {
        unsigned d = (unsigned)dst[e];
        unsigned p = atomicAdd(&cursor[d >> BSHIFT], 1u);
        bucketed[p] = ((d & 127u) << 17) | (unsigned)src[e];   // src < 2^17
    }
}

__global__ void bucket_place(const unsigned* __restrict__ bucketed,
                             const unsigned* __restrict__ bucketBase,
                             int* __restrict__ csrSrc, unsigned* __restrict__ rowEnd,
                             float* __restrict__ normIn) {
    __shared__ unsigned cnt128[128], cur[128];
    __shared__ unsigned eb[MAXB], ob[MAXB];
    int b = blockIdx.x;
    unsigned s0 = bucketBase[b];
    unsigned s1 = (b + 1 < NBUCK) ? bucketBase[b + 1] : (unsigned)N_EDGES;
    int cnt = (int)(s1 - s0);
    bool fits = cnt <= MAXB;
    int t = threadIdx.x;
    if (t < 128) cnt128[t] = 0u;
    __syncthreads();
    for (int i = t; i < cnt; i += 512) {
        unsigned v = bucketed[s0 + i];
        if (fits) eb[i] = v;
        atomicAdd(&cnt128[v >> 17], 1u);
    }
    __syncthreads();
    unsigned deg = (t < 128) ? cnt128[t] : 0u;
    __syncthreads();
    for (int off = 1; off < 128; off <<= 1) {
        unsigned a = (t < 128 && t >= off) ? cnt128[t - off] : 0u;
        __syncthreads();
        if (t < 128) cnt128[t] += a;
        __syncthreads();
    }
    if (t < 128) {
        unsigned incl = cnt128[t];
        cur[t] = incl - deg;               // local exclusive
        int node = b * 128 + t;
        if (node < N_NODES) {
            rowEnd[node] = s0 + incl;      // global inclusive prefix
            normIn[node] = deg ? rsqrtf((float)deg) : 0.0f;
        }
    }
    __syncthreads();
    if (fits) {
        for (int i = t; i < cnt; i += 512) {
            unsigned v = eb[i];
            unsigned p = atomicAdd(&cur[v >> 17], 1u);
            ob[p] = v & 0x1FFFFu;
        }
        __syncthreads();
        for (int i = t; i < cnt; i += 512)
            csrSrc[s0 + i] = (int)ob[i];
    } else {
        for (int i = t; i < cnt; i += 512) {
            unsigned v = bucketed[s0 + i];
            unsigned p = atomicAdd(&cur[v >> 17], 1u);
            csrSrc[s0 + p] = (int)(v & 0x1FFFFu);
        }
    }
}

// ============ datapath ============

// features * normOut -> fp8 rows (128 B)
__global__ void convert_kernel(const float* __restrict__ feat, const float* __restrict__ normOut,
                               unsigned char* __restrict__ out) {
    int gid = blockIdx.x * 256 + threadIdx.x;   // over N_NODES*16
    if (gid >= N_NODES * 16) return;
    int row = gid >> 4, j = gid & 15;
    float no = normOut[row];
    float4 v0 = ((const float4*)feat)[(size_t)row * 32 + j * 2];
    float4 v1 = ((const float4*)feat)[(size_t)row * 32 + j * 2 + 1];
    unsigned lo = 0, hi = 0;
    lo = __builtin_amdgcn_cvt_pk_fp8_f32(v0.x * no, v0.y * no, lo, false);
    lo = __builtin_amdgcn_cvt_pk_fp8_f32(v0.z * no, v0.w * no, lo, true);
    hi = __builtin_amdgcn_cvt_pk_fp8_f32(v1.x * no, v1.y * no, hi, false);
    hi = __builtin_amdgcn_cvt_pk_fp8_f32(v1.z * no, v1.w * no, hi, true);
    ((uint2*)out)[(size_t)row * 16 + j] = make_uint2(lo, hi);
}

__device__ __forceinline__ void accf8(float* a, uint2 v) {
    f32x2 p;
    p = __builtin_amdgcn_cvt_pk_f32_fp8(v.x, false); a[0] += p.x; a[1] += p.y;
    p = __builtin_amdgcn_cvt_pk_f32_fp8(v.x, true);  a[2] += p.x; a[3] += p.y;
    p = __builtin_amdgcn_cvt_pk_f32_fp8(v.y, false); a[4] += p.x; a[5] += p.y;
    p = __builtin_amdgcn_cvt_pk_f32_fp8(v.y, true);  a[6] += p.x; a[7] += p.y;
}

// repack 3 weights (fp32 KxN) into bf16 B-fragment order
__global__ void repack_kernel(const float* __restrict__ W0, const float* __restrict__ W1,
                              const float* __restrict__ W2,
                              unsigned short* __restrict__ Wp0, unsigned short* __restrict__ Wp1,
                              unsigned short* __restrict__ Wp2) {
    int which = blockIdx.x >> 3;
    const float* W = which == 0 ? W0 : which == 1 ? W1 : W2;
    unsigned short* Wp = which == 0 ? Wp0 : which == 1 ? Wp1 : Wp2;
    int tid = (blockIdx.x & 7) * 256 + threadIdx.x;
    int tile = tid >> 6, lane = tid & 63;
    int n_tile = tile >> 2, k_tile = tile & 3;
    int n = n_tile * 16 + (lane & 15);
    int k0 = k_tile * 32 + (lane >> 4) * 8;
    unsigned short v[8];
#pragma unroll
    for (int j = 0; j < 8; ++j)
        v[j] = f2bf(W[(size_t)(k0 + j) * 128 + n]);
    uint4 o;
    o.x = (unsigned)v[0] | ((unsigned)v[1] << 16);
    o.y = (unsigned)v[2] | ((unsigned)v[3] << 16);
    o.z = (unsigned)v[4] | ((unsigned)v[5] << 16);
    o.w = (unsigned)v[6] | ((unsigned)v[7] << 16);
    *(uint4*)&Wp[(size_t)(tile * 64 + lane) * 8] = o;
}

// ============ fused gather(fp8) + MFMA(bf16) + epilogue ============
// hgOut==null: store fp8 h' rows (scaled by postScale if non-null).
// hgOut!=null: skip stores; column-sum the relu output into hgOut (mean fusion).
__launch_bounds__(256)
__global__ void fused_layer(const unsigned char* __restrict__ h,
                            const int* __restrict__ csrSrc,
                            const unsigned* __restrict__ rowEnd,
                            const unsigned short* __restrict__ Wp,
                            const float* __restrict__ bias,
                            const float* __restrict__ normIn,
                            const float* __restrict__ postScale,
                            unsigned char* __restrict__ Out,
                            float* __restrict__ hgOut) {
    __shared__ unsigned short Ml[64 * LROW];   // 17408 B, bf16 staging
    __shared__ float csLDS[128];
    int tid = threadIdx.x;
    int slot = tid >> 4, lane16 = tid & 15;    // 16 slots x 16 lanes
    int rowBase = blockIdx.x * 64;
    const uint2* h2 = (const uint2*)h;
    if (tid < 128) csLDS[tid] = 0.f;

#pragma unroll
    for (int j = 0; j < 4; ++j) {
        int rloc = slot + 16 * j;
        int row = rowBase + rloc;
        float a[8] = {0.f, 0.f, 0.f, 0.f, 0.f, 0.f, 0.f, 0.f};
        if (row < N_NODES) {
            unsigned start = row ? rowEnd[row - 1] : 0u;
            unsigned end = rowEnd[row];
            unsigned k = start;
            for (; k + 8 <= end; k += 8) {
                int s[8];
#pragma unroll
                for (int u = 0; u < 8; ++u) s[u] = csrSrc[k + u];
                uint2 v[8];
#pragma unroll
                for (int u = 0; u < 8; ++u) v[u] = h2[(size_t)s[u] * 16 + lane16];
#pragma unroll
                for (int u = 0; u < 8; ++u) accf8(a, v[u]);
            }
            if (k + 4 <= end) {
                int s[4];
#pragma unroll
                for (int u = 0; u < 4; ++u) s[u] = csrSrc[k + u];
                uint2 v[4];
#pragma unroll
                for (int u = 0; u < 4; ++u) v[u] = h2[(size_t)s[u] * 16 + lane16];
#pragma unroll
                for (int u = 0; u < 4; ++u) accf8(a, v[u]);
                k += 4;
            }
            for (; k < end; ++k) {
                uint2 v = h2[(size_t)csrSrc[k] * 16 + lane16];
                accf8(a, v);
            }
        }
        uint4 o;
        o.x = (unsigned)f2bf(a[0]) | ((unsigned)f2bf(a[1]) << 16);
        o.y = (unsigned)f2bf(a[2]) | ((unsigned)f2bf(a[3]) << 16);
        o.z = (unsigned)f2bf(a[4]) | ((unsigned)f2bf(a[5]) << 16);
        o.w = (unsigned)f2bf(a[6]) | ((unsigned)f2bf(a[7]) << 16);
        *(uint4*)&Ml[rloc * LROW + lane16 * 8] = o;
    }
    __syncthreads();

    int wave = tid >> 6, lane = tid & 63;
    int mrow = lane & 15, quad = lane >> 4;
    int rloc = wave * 16 + mrow;
    short8 afr[4];
#pragma unroll
    for (int kt = 0; kt < 4; ++kt)
        afr[kt] = *(const short8*)&Ml[rloc * LROW + kt * 32 + quad * 8];

    f32x4 acc[8];
#pragma unroll
    for (int nt = 0; nt < 8; ++nt) {
        f32x4 c = {0.f, 0.f, 0.f, 0.f};
#pragma unroll
        for (int kt = 0; kt < 4; ++kt) {
            short8 b = *(const short8*)&Wp[(size_t)((nt * 4 + kt) * 64 + lane) * 8];
            c = __builtin_amdgcn_mfma_f32_16x16x32_bf16(afr[kt], b, c, 0, 0, 0);
        }
        acc[nt] = c;
    }

    int col0 = lane & 15;
    if (hgOut == nullptr) {
#pragma unroll
        for (int r = 0; r < 4; ++r) {
            int row = rowBase + wave * 16 + quad * 4 + r;
            if (row >= N_NODES) continue;
            float ni = normIn[row];
            float po = postScale ? postScale[row] : 1.0f;
#pragma unroll
            for (int nt = 0; nt < 8; ++nt) {
                float v = fmaxf(fmaf(acc[nt][r], ni, bias[nt * 16 + col0]), 0.f) * po;
                Out[(size_t)row * 128 + nt * 16 + col0] = f2fp8(v);
            }
        }
    } else {
#pragma unroll
        for (int nt = 0; nt < 8; ++nt) {
            float s = 0.f;
#pragma unroll
            for (int r = 0; r < 4; ++r) {
                int row = rowBase + wave * 16 + quad * 4 + r;
                if (row < N_NODES) {
                    float ni = normIn[row];
                    s += fmaxf(fmaf(acc[nt][r], ni, bias[nt * 16 + col0]), 0.f);
                }
            }
            s += __shfl_xor(s, 16, 64);
            s += __shfl_xor(s, 32, 64);
            if (quad == 0) atomicAdd(&csLDS[nt * 16 + col0], s);
        }
        __syncthreads();
        if (tid < 128) atomicAdd(&hgOut[tid], csLDS[tid]);
    }
}

__global__ void final_kernel(const float* __restrict__ hg, const float* __restrict__ Wr,
                             const float* __restrict__ br, float* __restrict__ out) {
    int j = threadIdx.x;
    if (j < N_PRED) {
        float acc = br[j];
        const float inv = 1.0f / (float)N_NODES;
        for (int k = 0; k < HID; ++k)
            acc = fmaf(hg[k] * inv, Wr[k * N_PRED + j], acc);
        out[j] = acc;
    }
}

extern "C" void kernel_launch(void* const* d_in, const int* in_sizes, int n_in,
                              void* d_out, int out_size, void* d_ws, size_t ws_size,
                              hipStream_t stream) {
    const float* features = (const float*)d_in[0];
    const float* W0 = (const float*)d_in[1];
    const float* b0 = (const float*)d_in[2];
    const float* W1 = (const float*)d_in[3];
    const float* b1 = (const float*)d_in[4];
    const float* W2 = (const float*)d_in[5];
    const float* b2 = (const float*)d_in[6];
    const float* Wr = (const float*)d_in[7];
    const float* br = (const float*)d_in[8];
    const int* src = (const int*)d_in[9];
    const int* dst = (const int*)d_in[10];
    float* out = (float*)d_out;

    char* ws = (char*)d_ws;
    size_t off = 0;
    auto alloc = [&](size_t bytes) -> void* {
        void* p = ws + off;
        off = (off + bytes + 255) & ~(size_t)255;
        return p;
    };
    unsigned char* buf0 = (unsigned char*)alloc((size_t)N_PAD * HID);   // 12.8 MB fp8
    unsigned char* buf1 = (unsigned char*)alloc((size_t)N_PAD * HID);
    unsigned short* Wp0 = (unsigned short*)alloc(128 * 128 * 2);
    unsigned short* Wp1 = (unsigned short*)alloc(128 * 128 * 2);
    unsigned short* Wp2 = (unsigned short*)alloc(128 * 128 * 2);
    unsigned* degOut = (unsigned*)alloc(N_NODES * 4);
    float* normOut = (float*)alloc(N_NODES * 4);
    float* normIn = (float*)alloc(N_NODES * 4);
    unsigned* rowEnd = (unsigned*)alloc(N_NODES * 4);
    unsigned* blockHist = (unsigned*)alloc((size_t)NBUCK * NCHUNK * 4);
    unsigned* bucketTotal = (unsigned*)alloc(NBUCK * 4);
    unsigned* bucketBase = (unsigned*)alloc((NBUCK + 1) * 4);
    unsigned* bucketed = (unsigned*)alloc((size_t)N_EDGES * 4);
    int* csrSrc = (int*)alloc((size_t)N_EDGES * 4);
    float* hg = (float*)alloc(HID * 4);

    hipMemsetAsync(degOut, 0, N_NODES * 4, stream);
    hipMemsetAsync(hg, 0, HID * 4, stream);

    deg_kernel<<<(N_EDGES / 4 + 255) / 256, 256, 0, stream>>>((const int4*)src, degOut);
    bucket_hist<<<NCHUNK, 512, 0, stream>>>(dst, blockHist);
    bucket_total<<<NBUCK, 256, 0, stream>>>(blockHist, bucketTotal);
    bucket_scan<<<1, 1024, 0, stream>>>(bucketTotal, bucketBase);
    bucket_cursor<<<NBUCK, 256, 0, stream>>>(blockHist, bucketBase);
    bucket_scatter<<<NCHUNK, 512, 0, stream>>>(src, dst, blockHist, bucketed);
    bucket_place<<<NBUCK, 512, 0, stream>>>(bucketed, bucketBase, csrSrc, rowEnd, normIn);
    normout_kernel<<<(N_NODES + 255) / 256, 256, 0, stream>>>(degOut, normOut);

    convert_kernel<<<(N_NODES * 16 + 255) / 256, 256, 0, stream>>>(features, normOut, buf0);
    repack_kernel<<<24, 256, 0, stream>>>(W0, W1, W2, Wp0, Wp1, Wp2);

    int fusedGrid = (N_NODES + 63) / 64;   // 1563

    fused_layer<<<fusedGrid, 256, 0, stream>>>(buf0, csrSrc, rowEnd, Wp0, b0, normIn, normOut,
                                               buf1, (float*)nullptr);
    fused_layer<<<fusedGrid, 256, 0, stream>>>(buf1, csrSrc, rowEnd, Wp1, b1, normIn, normOut,
                                               buf0, (float*)nullptr);
    fused_layer<<<fusedGrid, 256, 0, stream>>>(buf0, csrSrc, rowEnd, Wp2, b2, normIn,
                                               (const float*)nullptr, (unsigned char*)nullptr, hg);

    final_kernel<<<1, 64, 0, stream>>>(hg, Wr, br, out);
}